// Round 10
// baseline (490.050 us; speedup 1.0000x reference)
//
#include <hip/hip_runtime.h>
#include <math.h>

#define WIN 11
#define PAD 5
#define TW 64              // tile width = wave width

struct GW { float g[WIN]; };
struct Pyr { float *a1, *b1, *a2, *b2, *a3, *b3, *a4, *b4; };

// ---------------------------------------------------------------------------
// Wave-autonomous SSIM tile (R9-verified STEP body). One wave streams a
// 64-wide x TH_-tall output tile, no block barriers. Per row t: prefetched
// global load -> wave-private LDS row (74 float2, wave_barrier-ordered) ->
// 11 ds_read_b64/lane -> H-conv -> shift-register V-conv -> emit row t-10.
// EMIT (L0 only): cascaded local pyramid in p/q domain — pair-row pooling +
// shfl_down(1/2/4/8) column pooling emits L1,L2,L3,L4 for this tile
// (all 2^k-aligned, fully tile-local). a=(P+Q)/2, b=(P-Q)/2 at store.
// ---------------------------------------------------------------------------
template<int TH_, bool EMIT>
__device__ __forceinline__ float ssim_wave_tile(
    const float* __restrict__ p1, const float* __restrict__ p2,
    int W, int X0, int Y0, const GW& gw, float2* __restrict__ rb,
    const Pyr* pyr)
{
    const int lane = threadIdx.x & 63;
    const int gx = X0 + lane;
    const bool cval = gx < W;                              // false only for L4 lanes 32+
    const int hx   = (lane < 5) ? (X0 - 5 + lane) : (X0 + 59 + lane);
    const bool hval = (lane < 10) && ((unsigned)hx < (unsigned)W);
    const int hpos = (lane < 5) ? lane : (64 + lane);      // 0..4 | 69..73
    const int cpos = 5 + lane;

    float vMp[11], vSp[11], vMq[11], vSq[11];
#pragma unroll
    for (int k = 0; k < 11; ++k) { vMp[k] = 0.f; vSp[k] = 0.f; vMq[k] = 0.f; vSq[k] = 0.f; }

    float part = 0.f;
    float pprev = 0.f, qprev = 0.f;
    float P1prev = 0.f, Q1prev = 0.f;
    float P2prev = 0.f, Q2prev = 0.f;
    float P3prev = 0.f, Q3prev = 0.f;
    float a, b, ah, bh;

    auto LOAD = [&](int t, float& oa, float& ob, float& oah, float& obh) {
        int y = Y0 - PAD + t;
        oa = 0.f; ob = 0.f; oah = 0.f; obh = 0.f;
        if ((unsigned)y < (unsigned)W) {
            const float* r1 = p1 + (size_t)y * W;
            const float* r2 = p2 + (size_t)y * W;
            if (cval) { oa  = r1[gx]; ob  = r2[gx]; }
            if (hval) { oah = r1[hx]; obh = r2[hx]; }
        }
    };

    LOAD(0, a, b, ah, bh);

#pragma unroll 2
    for (int t = 0; t < TH_ + 10; ++t) {
        // prefetch next row while computing this one
        float na, nb, nah, nbh;
        LOAD(t + 1, na, nb, nah, nbh);

        float p = a + b, q = a - b;
        float ph = ah + bh, qh = ah - bh;
        rb[cpos] = make_float2(p, q);
        if (lane < 10) rb[hpos] = make_float2(ph, qh);
        __builtin_amdgcn_wave_barrier();   // writes -> reads (cross-lane RAW)

        float hp = 0.f, hq = 0.f, hpp = 0.f, hqq = 0.f;
#pragma unroll
        for (int j = 0; j < WIN; ++j) {
            float2 v = rb[lane + j];
            float g = gw.g[j];
            hp  = fmaf(g, v.x, hp);
            hpp = fmaf(g, v.x * v.x, hpp);
            hq  = fmaf(g, v.y, hq);
            hqq = fmaf(g, v.y * v.y, hqq);
        }
        __builtin_amdgcn_wave_barrier();   // reads -> next row's writes (WAR)

        // V-conv shift-register accumulate: slot k <- g[10-k]*h (== g[t-o])
#pragma unroll
        for (int k = 0; k < 11; ++k) {
            float g = gw.g[10 - k];
            vMp[k] = fmaf(g, hp,  vMp[k]);
            vSp[k] = fmaf(g, hpp, vSp[k]);
            vMq[k] = fmaf(g, hq,  vMq[k]);
            vSq[k] = fmaf(g, hqq, vSq[k]);
        }

        if (EMIT) {
            if (t >= 6 && t <= TH_ + 4 && (t & 1) == 0) {   // L1 row from rows (t-1,t)
                float sp_ = p + pprev, sq_ = q + qprev;
                float sp2 = sp_ + __shfl_down(sp_, 1, 64);
                float sq2 = sq_ + __shfl_down(sq_, 1, 64);
                float P1 = sp2 * 0.25f, Q1 = sq2 * 0.25f;   // valid at lanes %2==0
                int yo = (t - 6) >> 1;
                if ((lane & 1) == 0) {
                    size_t oo = (size_t)((Y0 >> 1) + yo) * 256 + ((X0 >> 1) + (lane >> 1));
                    pyr->a1[oo] = (P1 + Q1) * 0.5f;
                    pyr->b1[oo] = (P1 - Q1) * 0.5f;
                }
                if (yo & 1) {                               // complete L2 row
                    float s2p = P1prev + P1, s2q = Q1prev + Q1;
                    s2p += __shfl_down(s2p, 2, 64);
                    s2q += __shfl_down(s2q, 2, 64);
                    float P2 = s2p * 0.25f, Q2 = s2q * 0.25f;   // lanes %4==0
                    int zo = yo >> 1;
                    if ((lane & 3) == 0) {
                        size_t oo = (size_t)((Y0 >> 2) + zo) * 128 + ((X0 >> 2) + (lane >> 2));
                        pyr->a2[oo] = (P2 + Q2) * 0.5f;
                        pyr->b2[oo] = (P2 - Q2) * 0.5f;
                    }
                    if (zo & 1) {                           // complete L3 row
                        float s3p = P2prev + P2, s3q = Q2prev + Q2;
                        s3p += __shfl_down(s3p, 4, 64);
                        s3q += __shfl_down(s3q, 4, 64);
                        float P3 = s3p * 0.25f, Q3 = s3q * 0.25f;  // lanes %8==0
                        int wo = zo >> 1;
                        if ((lane & 7) == 0) {
                            size_t oo = (size_t)((Y0 >> 3) + wo) * 64 + ((X0 >> 3) + (lane >> 3));
                            pyr->a3[oo] = (P3 + Q3) * 0.5f;
                            pyr->b3[oo] = (P3 - Q3) * 0.5f;
                        }
                        if (wo & 1) {                       // complete L4 row
                            float s4p = P3prev + P3, s4q = Q3prev + Q3;
                            s4p += __shfl_down(s4p, 8, 64);
                            s4q += __shfl_down(s4q, 8, 64);
                            float P4 = s4p * 0.25f, Q4 = s4q * 0.25f;  // lanes %16==0
                            int uo = wo >> 1;
                            if ((lane & 15) == 0) {
                                size_t oo = (size_t)((Y0 >> 4) + uo) * 32 + ((X0 >> 4) + (lane >> 4));
                                pyr->a4[oo] = (P4 + Q4) * 0.5f;
                                pyr->b4[oo] = (P4 - Q4) * 0.5f;
                            }
                        } else { P3prev = P3; Q3prev = Q3; }
                    } else { P2prev = P2; Q2prev = Q2; }
                } else { P1prev = P1; Q1prev = Q1; }
            }
            pprev = p; qprev = q;
        }

        if (t >= 10) {                               // output row o = t-10 from slot 0
            int o = t - 10;
            bool yok = (unsigned)(Y0 + o) < (unsigned)W;   // false only for L4 tail
            float Mp = vMp[0], Sp_ = vSp[0], Mq = vMq[0], Sq_ = vSq[0];
            const float C1v = 1e-4f, C2v = 9e-4f;
            float A = Mp * Mp, B = Mq * Mq;
            float ABp = A + B, ABm = A - B;
            float SSp = Sp_ + Sq_, SSm = Sp_ - Sq_;
            float n1 = fmaf(0.5f, ABm, C1v);         // 2*m12 + C1
            float n2 = fmaf(0.5f, SSm - ABm, C2v);   // 2*s12 + C2
            float e1 = fmaf(0.5f, ABp, C1v);         // m1^2+m2^2 + C1
            float e2 = fmaf(0.5f, SSp - ABp, C2v);   // s1+s2 + C2
            float v = (n1 * n2) * __builtin_amdgcn_rcpf(e1 * e2);
            part += (cval && yok) ? v : 0.f;
        }

        // shift down, clear slot 10
#pragma unroll
        for (int k = 0; k < 10; ++k) {
            vMp[k] = vMp[k + 1]; vSp[k] = vSp[k + 1];
            vMq[k] = vMq[k + 1]; vSq[k] = vSq[k + 1];
        }
        vMp[10] = 0.f; vSp[10] = 0.f; vMq[10] = 0.f; vSq[10] = 0.f;

        a = na; b = nb; ah = nah; bh = nbh;
    }

    return part;
}

// ---- L0: 64x32 tiles, 128/img x 48 = 6144 waves (1536 blocks); emits L1-L4 --
__global__ __launch_bounds__(256, 5) void ssim_l0_kernel(
    const float* __restrict__ i1, const float* __restrict__ i2,
    float* __restrict__ a1, float* __restrict__ b1,
    float* __restrict__ a2, float* __restrict__ b2,
    float* __restrict__ a3, float* __restrict__ b3,
    float* __restrict__ a4, float* __restrict__ b4,
    double* __restrict__ acc, GW gw)
{
    __shared__ float2 rbs[4][80];
    const int wid = threadIdx.x >> 6;
    const int w = blockIdx.x * 4 + wid;
    const int img = w >> 7;
    const int tt = w & 127;
    const int tx = tt & 7, ty = tt >> 3;          // 8 x 16 tiles
    const size_t off = (size_t)img * 512 * 512;
    Pyr pyr;
    pyr.a1 = a1 + (size_t)img * 256 * 256;  pyr.b1 = b1 + (size_t)img * 256 * 256;
    pyr.a2 = a2 + (size_t)img * 128 * 128;  pyr.b2 = b2 + (size_t)img * 128 * 128;
    pyr.a3 = a3 + (size_t)img * 64 * 64;    pyr.b3 = b3 + (size_t)img * 64 * 64;
    pyr.a4 = a4 + (size_t)img * 32 * 32;    pyr.b4 = b4 + (size_t)img * 32 * 32;

    float part = ssim_wave_tile<32, true>(i1 + off, i2 + off, 512,
                                          tx * TW, ty * 32, gw, rbs[wid], &pyr);
#pragma unroll
    for (int o = 32; o > 0; o >>= 1) part += __shfl_down(part, o, 64);
    if ((threadIdx.x & 63) == 0) atomicAdd(acc, (double)part);
}

// ---- L1..L4: 43 tiles/img x 48 = 2064 waves (516 blocks) ----
__global__ __launch_bounds__(256, 4) void ssim_rest_kernel(
    const float* __restrict__ a1, const float* __restrict__ b1,
    const float* __restrict__ a2, const float* __restrict__ b2,
    const float* __restrict__ a3, const float* __restrict__ b3,
    const float* __restrict__ a4, const float* __restrict__ b4,
    double* __restrict__ acc, GW gw)
{
    __shared__ float2 rbs[4][80];
    const int wid = threadIdx.x >> 6;
    const int w = blockIdx.x * 4 + wid;
    const int img = w / 43;
    const int r = w - img * 43;
    int lvl, tx, ty;
    if (r < 32)      { lvl = 1; tx = r & 3;        ty = r >> 2; }       // 4x8
    else if (r < 40) { lvl = 2; tx = (r - 32) & 1; ty = (r - 32) >> 1; } // 2x4
    else if (r < 42) { lvl = 3; tx = 0; ty = r - 40; }                  // 1x2
    else             { lvl = 4; tx = 0; ty = 0; }
    const int W = 512 >> lvl;
    const float* p1; const float* p2;
    switch (lvl) {
      case 1:  p1 = a1; p2 = b1; break;
      case 2:  p1 = a2; p2 = b2; break;
      case 3:  p1 = a3; p2 = b3; break;
      default: p1 = a4; p2 = b4; break;
    }
    const size_t off = (size_t)img * W * W;

    float part = ssim_wave_tile<32, false>(p1 + off, p2 + off, W,
                                           tx * TW, ty * 32, gw, rbs[wid], nullptr);
#pragma unroll
    for (int o = 32; o > 0; o >>= 1) part += __shfl_down(part, o, 64);
    if ((threadIdx.x & 63) == 0) atomicAdd(acc + lvl, (double)part);
}

__global__ void final_kernel(const double* __restrict__ acc, float* __restrict__ out)
{
    double loss = 0.0;
#pragma unroll
    for (int l = 0; l < 5; ++l) {
        double cnt = 48.0 * (double)(512 >> l) * (double)(512 >> l);
        loss += 1.0 - acc[l] / cnt;
    }
    out[0] = (float)loss;
}

extern "C" void kernel_launch(void* const* d_in, const int* in_sizes, int n_in,
                              void* d_out, int out_size, void* d_ws, size_t ws_size,
                              hipStream_t stream)
{
    const float* img1 = (const float*)d_in[0];
    const float* img2 = (const float*)d_in[1];
    float* out = (float*)d_out;

    // 1D gaussian (sigma=1.5, k=11), matches reference construction
    GW gw;
    double gs[WIN], sum = 0.0;
    for (int i = 0; i < WIN; ++i) {
        double ax = (double)i - 5.0;
        gs[i] = exp(-(ax * ax) / 4.5);
        sum += gs[i];
    }
    for (int i = 0; i < WIN; ++i) gw.g[i] = (float)(gs[i] / sum);

    // workspace: 64B header (5 double acc), then pyramid
    double* acc = (double*)d_ws;
    float* base = (float*)((char*)d_ws + 64);
    const size_t n1 = 48ull * 256 * 256;
    const size_t n2 = 48ull * 128 * 128;
    const size_t n3 = 48ull * 64 * 64;
    const size_t n4 = 48ull * 32 * 32;
    float* a1 = base;      float* b1 = a1 + n1;
    float* a2 = b1 + n1;   float* b2 = a2 + n2;
    float* a3 = b2 + n2;   float* b3 = a3 + n3;
    float* a4 = b3 + n3;   float* b4 = a4 + n4;

    hipMemsetAsync(acc, 0, 5 * sizeof(double), stream);

    hipLaunchKernelGGL(ssim_l0_kernel, dim3(1536), dim3(256), 0, stream,
                       img1, img2, a1, b1, a2, b2, a3, b3, a4, b4, acc, gw);

    hipLaunchKernelGGL(ssim_rest_kernel, dim3(516), dim3(256), 0, stream,
                       a1, b1, a2, b2, a3, b3, a4, b4, acc, gw);

    hipLaunchKernelGGL(final_kernel, dim3(1), dim3(1), 0, stream, acc, out);
}